// Round 9
// baseline (662.005 us; speedup 1.0000x reference)
//
#include <hip/hip_runtime.h>
#include <hip/hip_bf16.h>
#include <math.h>

// Relational Network fused pipeline for MI355X (gfx950).
// B=32, D=64, K=26, QST=256, G=[512x6, 28], AGG at layer 4.
//
// Round 9 changes vs round 8:
//  - k_fused K-loop: W fragments now staged via ASYNC __builtin_amdgcn_global_load_lds
//    (width 16) into wave-PRIVATE double buffers in LDS; manual s_waitcnt vmcnt(4)
//    ping-pong (m97 structure). W leaves the VGPR/latency critical path: r8 was
//    latency-bound (MfmaUtil 21.5% ~= 77cyc MFMA / (77+250cyc exposed L2/L3 latency)).
//    LDS 64KB h + 64KB wbuf -> 1 block/CU, 8 waves; latency hidden structurally.
//  - k_prep: W4t/W5t transposes via 32x32 LDS tiles (both sides coalesced).

typedef __attribute__((ext_vector_type(8))) short bf16x8;   // 8 bf16 in 4 VGPRs
typedef __attribute__((ext_vector_type(4))) float f32x4;    // MFMA 16x16 accumulator

typedef __attribute__((address_space(1))) const unsigned int as1_u32;
typedef __attribute__((address_space(3))) unsigned int as3_u32;

__device__ __forceinline__ unsigned short f2bf(float f) {
    union { float f; unsigned u; } x; x.f = f;
    unsigned r = x.u + 0x7fffu + ((x.u >> 16) & 1u);   // RNE
    return (unsigned short)(r >> 16);
}

#define MFMA16(a, b, c) __builtin_amdgcn_mfma_f32_16x16x32_bf16(a, b, c, 0, 0, 0)
#define WAITV4 asm volatile("s_waitcnt vmcnt(4)" ::: "memory")
#define WAITV0 asm volatile("s_waitcnt vmcnt(0)" ::: "memory")
#define MEMBAR asm volatile("" ::: "memory")

// async 16B/lane global->LDS: lds base must be wave-uniform; lane i lands at lds+16*i
__device__ __forceinline__ void stage16(const unsigned short* g, unsigned short* lds) {
    __builtin_amdgcn_global_load_lds((as1_u32*)g, (as3_u32*)lds, 16, 0, 0);
}

// ---------------- prep ----------------
// Wp layout per layer: [wv(8)][s(16)][jj(4)][lane(64)][j(8)] bf16,
//   value = W[n][k], n = (wv*4+jj)*16 + (lane&15), k = s*32 + (lane>>4)*8 + j.
// Block ranges: [0,384) Wp pack | [384,768) W4 transpose | [768,1024) W5 transpose
//               | [1024,1088) S=0 | [1088,1600) U/V
__global__ void k_prep(const float* __restrict__ W1, const float* __restrict__ W2,
                       const float* __restrict__ W3, const float* __restrict__ W0,
                       const float* __restrict__ W4, const float* __restrict__ W5,
                       const float* __restrict__ x,  const float* __restrict__ b0,
                       unsigned short* __restrict__ Wp,   // [3][262144] bf16
                       float* __restrict__ W4t,           // [768][512] fp32
                       float* __restrict__ W5t,           // [512][512] fp32
                       float* __restrict__ S,             // [32][512] fp32 (zeroed)
                       float* __restrict__ U, float* __restrict__ V)
{
    int bi = blockIdx.x;
    int t = threadIdx.x;
    if (bi < 384) {
        // one thread = one 8-elem fragment run (16B write-coalesced)
        int T = bi * 256 + t;                 // [0, 98304)
        int l = T >> 15, r = T & 32767;
        int lane = r & 63, jj = (r >> 6) & 3, s = (r >> 8) & 15, wv = (r >> 12) & 7;
        int n  = (wv * 4 + jj) * 16 + (lane & 15);
        int kb = s * 32 + (lane >> 4) * 8;
        const float* W = (l == 0) ? W1 : (l == 1) ? W2 : W3;
        const float4* src = (const float4*)&W[n * 512 + kb];
        float4 v0 = src[0], v1 = src[1];
        ushort4 p0, p1;
        p0.x = f2bf(v0.x); p0.y = f2bf(v0.y); p0.z = f2bf(v0.z); p0.w = f2bf(v0.w);
        p1.x = f2bf(v1.x); p1.y = f2bf(v1.y); p1.z = f2bf(v1.z); p1.w = f2bf(v1.w);
        ushort4* dst = (ushort4*)&Wp[(size_t)T * 8];
        dst[0] = p0; dst[1] = p1;
    } else if (bi < 768) {
        // W4 [512][768] -> W4t [768][512], 32x32 LDS tiles, both sides coalesced
        int tile = bi - 384;                  // 0..383 = 24 (k) x 16 (o)
        int tk = tile % 24, to = tile / 24;
        __shared__ float tl[32][33];
        int tx = t & 31, ty = t >> 5;         // 32 x 8
        #pragma unroll
        for (int i = 0; i < 4; ++i)
            tl[ty + i * 8][tx] = W4[(to * 32 + ty + i * 8) * 768 + tk * 32 + tx];
        __syncthreads();
        #pragma unroll
        for (int i = 0; i < 4; ++i)
            W4t[(tk * 32 + ty + i * 8) * 512 + to * 32 + tx] = tl[tx][ty + i * 8];
    } else if (bi < 1024) {
        // W5 [512][512] -> W5t [512][512] transpose
        int tile = bi - 768;                  // 0..255 = 16 x 16
        int tk = tile & 15, to = tile >> 4;
        __shared__ float tl[32][33];
        int tx = t & 31, ty = t >> 5;
        #pragma unroll
        for (int i = 0; i < 4; ++i)
            tl[ty + i * 8][tx] = W5[(to * 32 + ty + i * 8) * 512 + tk * 32 + tx];
        __syncthreads();
        #pragma unroll
        for (int i = 0; i < 4; ++i)
            W5t[(tk * 32 + ty + i * 8) * 512 + to * 32 + tx] = tl[tx][ty + i * 8];
    } else if (bi < 1088) {
        S[(bi - 1024) * 256 + t] = 0.f;
    } else {
        // ---- U/V: 512 blocks, one per (b, qg, half) ----
        int id = bi - 1088;
        int b = id >> 4, qg = (id >> 1) & 7, half = id & 1;
        __shared__ float xs[8][26];
        if (t < 8 * 26) xs[t / 26][t % 26] = x[(b * 64 + qg * 8 + t / 26) * 26 + t % 26];
        __syncthreads();
        int o = half * 256 + t;
        float u[8] = {0,0,0,0,0,0,0,0}, v[8] = {0,0,0,0,0,0,0,0};
        for (int k = 0; k < 26; ++k) {
            float wa = W0[o * 52 + k];
            float wb = W0[o * 52 + 26 + k];
            #pragma unroll
            for (int q = 0; q < 8; ++q) {
                u[q] = fmaf(xs[q][k], wa, u[q]);
                v[q] = fmaf(xs[q][k], wb, v[q]);
            }
        }
        float bb = b0[o];
        #pragma unroll
        for (int q = 0; q < 8; ++q) {
            U[(size_t)((b * 64 + qg * 8 + q)) * 512 + o] = u[q] + bb;  // b0 folded into U
            V[(size_t)((b * 64 + qg * 8 + q)) * 512 + o] = v[q];
        }
    }
}
#define NPREP_BLOCKS 1600

// ---------------- fused heavy layers 1..3 (transposed compute, async W) ----------
// One block per (b,p): 64 pair-rows m. h tile 64x512 bf16 in LDS, XOR-swizzled
// 16B granules: (m,k) at m*512 + ((k>>3)^(m&7))*8 + (k&7).
// 8 waves; wave w computes out-features n in [w*64, w*64+64):
// acc[nt][mt_]: n = w*64 + nt*16 + q4*4 + r, m = mt_*16 + i16.
// W staged per-wave into private LDS double buffers via global_load_lds.
__global__ __launch_bounds__(512) void k_fused(
    const float* __restrict__ U, const float* __restrict__ V,
    const unsigned short* __restrict__ Wp,
    const float* __restrict__ b1, const float* __restrict__ b2, const float* __restrict__ b3,
    float* __restrict__ S)
{
    __shared__ unsigned short hsm[64 * 512];   // 64 KiB h tile
    __shared__ unsigned short wsm[8 * 4096];   // 64 KiB: [wave][buf(2)][jj(4)][lane(64)][j(8)]
    int t = threadIdx.x;
    int blk = blockIdx.x;
    int id = (blk & 7) * 256 + (blk >> 3);     // XCD-contiguous tile ids
    int b = id >> 6, p = id & 63;

    // ---- stage h0 = relu(U[b,q,:] + V[b,p,:]) into LDS (bf16, swizzled) ----
    const float4* U4 = (const float4*)(U + (size_t)(b * 64) * 512);
    const float4* V4 = (const float4*)(V + (size_t)(b * 64 + p) * 512);
    #pragma unroll 1
    for (int it = 0; it < 16; ++it) {
        int f = it * 512 + t;
        int q = f >> 7, oq = f & 127;
        float4 uu = U4[q * 128 + oq];
        float4 vv = V4[oq];
        ushort4 pk;
        pk.x = f2bf(fmaxf(uu.x + vv.x, 0.f));
        pk.y = f2bf(fmaxf(uu.y + vv.y, 0.f));
        pk.z = f2bf(fmaxf(uu.z + vv.z, 0.f));
        pk.w = f2bf(fmaxf(uu.w + vv.w, 0.f));
        int g = oq >> 1, hh = oq & 1;
        *(ushort4*)&hsm[q * 512 + ((g ^ (q & 7)) << 3) + hh * 4] = pk;
    }

    int wave = t >> 6, lane = t & 63;
    int i16 = lane & 15, q4 = lane >> 4;
    int xr = i16 & 7;                       // m-invariant part of the swizzle
    unsigned short* wb = &wsm[wave * 4096]; // wave-private: 2 bufs x 2048 shorts

    #pragma unroll 1
    for (int l = 0; l < 3; ++l) {
        const float* bl = (l == 0) ? b1 : (l == 1) ? b2 : b3;
        __syncthreads();   // h ready; also drains vmcnt (compiler emits full wait)

        f32x4 acc[4][4];   // [nt][mt_]
        #pragma unroll
        for (int nt = 0; nt < 4; ++nt)
            #pragma unroll
            for (int mt_ = 0; mt_ < 4; ++mt_)
                acc[nt][mt_] = (f32x4){0.f, 0.f, 0.f, 0.f};

        // W source: per-lane 16B runs; s at +2048 shorts, jj at +512 shorts
        const unsigned short* Wb0 = Wp + (size_t)l * 262144 + wave * 32768 + lane * 8;
        const unsigned short* Ab0 = &hsm[i16 * 512];

        // prologue: stage s=0 into buf0
        {
            const unsigned short* gs = Wb0;
            stage16(gs,        wb);
            stage16(gs + 512,  wb + 512);
            stage16(gs + 1024, wb + 1024);
            stage16(gs + 1536, wb + 1536);
        }
        #pragma unroll 1
        for (int s = 0; s < 15; ++s) {
            MEMBAR;                          // fence: prior ds_reads can't sink below
            {   // stage s+1 into the other buffer (async, no regs)
                const unsigned short* gs = Wb0 + (s + 1) * 2048;
                unsigned short* lb = wb + ((s + 1) & 1) * 2048;
                stage16(gs,        lb);
                stage16(gs + 512,  lb + 512);
                stage16(gs + 1024, lb + 1024);
                stage16(gs + 1536, lb + 1536);
            }
            WAITV4;                          // batch s landed (in-order retire)
            const unsigned short* wr = wb + (s & 1) * 2048 + lane * 8;
            bf16x8 w[4], a[4];
            #pragma unroll
            for (int nt = 0; nt < 4; ++nt)
                w[nt] = *(const bf16x8*)(wr + nt * 512);
            int g = ((s * 4 + q4) ^ xr) * 8;
            #pragma unroll
            for (int mt_ = 0; mt_ < 4; ++mt_)
                a[mt_] = *(const bf16x8*)(Ab0 + g + mt_ * 8192);
            #pragma unroll
            for (int nt = 0; nt < 4; ++nt)
                #pragma unroll
                for (int mt_ = 0; mt_ < 4; ++mt_)
                    acc[nt][mt_] = MFMA16(w[nt], a[mt_], acc[nt][mt_]);
        }
        {   // s = 15 (drain)
            WAITV0;
            const unsigned short* wr = wb + 2048 + lane * 8;   // 15&1 = 1
            bf16x8 w[4], a[4];
            #pragma unroll
            for (int nt = 0; nt < 4; ++nt)
                w[nt] = *(const bf16x8*)(wr + nt * 512);
            int g = ((15 * 4 + q4) ^ xr) * 8;
            #pragma unroll
            for (int mt_ = 0; mt_ < 4; ++mt_)
                a[mt_] = *(const bf16x8*)(Ab0 + g + mt_ * 8192);
            #pragma unroll
            for (int nt = 0; nt < 4; ++nt)
                #pragma unroll
                for (int mt_ = 0; mt_ < 4; ++mt_)
                    acc[nt][mt_] = MFMA16(w[nt], a[mt_], acc[nt][mt_]);
        }
        __syncthreads();   // all reads of h done before overwrite

        if (l < 2) {
            // bias + relu -> 4 consecutive n per thread -> ds_write_b64
            #pragma unroll 1
            for (int nt = 0; nt < 4; ++nt) {
                float4 bb = *(const float4*)&bl[wave * 64 + nt * 16 + q4 * 4];
                int G = wave * 8 + nt * 2 + (q4 >> 1);    // n-granule index
                int nin = (q4 & 1) * 4;                   // short offset in granule
                #pragma unroll
                for (int mt_ = 0; mt_ < 4; ++mt_) {
                    int m = mt_ * 16 + i16;
                    ushort4 pk;
                    pk.x = f2bf(fmaxf(acc[nt][mt_][0] + bb.x, 0.f));
                    pk.y = f2bf(fmaxf(acc[nt][mt_][1] + bb.y, 0.f));
                    pk.z = f2bf(fmaxf(acc[nt][mt_][2] + bb.z, 0.f));
                    pk.w = f2bf(fmaxf(acc[nt][mt_][3] + bb.w, 0.f));
                    *(ushort4*)&hsm[m * 512 + ((G ^ (m & 7)) << 3) + nin] = pk;
                }
            }
        } else {
            // layer 3: bias + relu + sum over all 64 m -> atomicAdd S[b][n]
            #pragma unroll 1
            for (int nt = 0; nt < 4; ++nt) {
                float4 bb = *(const float4*)&bl[wave * 64 + nt * 16 + q4 * 4];
                float s0 = 0.f, s1 = 0.f, s2s = 0.f, s3 = 0.f;
                #pragma unroll
                for (int mt_ = 0; mt_ < 4; ++mt_) {
                    s0 += fmaxf(acc[nt][mt_][0] + bb.x, 0.f);
                    s1 += fmaxf(acc[nt][mt_][1] + bb.y, 0.f);
                    s2s += fmaxf(acc[nt][mt_][2] + bb.z, 0.f);
                    s3 += fmaxf(acc[nt][mt_][3] + bb.w, 0.f);
                }
                #pragma unroll
                for (int d = 1; d < 16; d <<= 1) {
                    s0 += __shfl_xor(s0, d);
                    s1 += __shfl_xor(s1, d);
                    s2s += __shfl_xor(s2s, d);
                    s3 += __shfl_xor(s3, d);
                }
                if (i16 == 0) {
                    float* dst = &S[b * 512 + wave * 64 + nt * 16 + q4 * 4];
                    atomicAdd(dst + 0, s0);
                    atomicAdd(dst + 1, s1);
                    atomicAdd(dst + 2, s2s);
                    atomicAdd(dst + 3, s3);
                }
            }
        }
    }
}

// ---------------- tail: layers 4,5,6 + log_softmax (one block per batch) ----
__global__ __launch_bounds__(512) void k_tail(
    const float* __restrict__ S, const float* __restrict__ qst,
    const float* __restrict__ W4t, const float* __restrict__ b4,
    const float* __restrict__ W5t, const float* __restrict__ b5,
    const float* __restrict__ W6, const float* __restrict__ b6,
    float* __restrict__ out)
{
    int b = blockIdx.x, t = threadIdx.x;
    __shared__ float z[768];
    __shared__ float h4[512];
    __shared__ float h5[512];
    __shared__ float logits[28];
    __shared__ float red[2];

    for (int i = t; i < 768; i += 512)
        z[i] = (i < 512) ? S[b * 512 + i] : qst[b * 256 + (i - 512)];
    __syncthreads();
    {   // layer 4: 768 -> 512, relu
        float acc = b4[t];
        for (int k = 0; k < 768; ++k) acc = fmaf(W4t[k * 512 + t], z[k], acc);
        h4[t] = fmaxf(acc, 0.f);
    }
    __syncthreads();
    {   // layer 5: 512 -> 512, relu
        float acc = b5[t];
        for (int k = 0; k < 512; ++k) acc = fmaf(W5t[k * 512 + t], h4[k], acc);
        h5[t] = fmaxf(acc, 0.f);
    }
    __syncthreads();
    {   // layer 6: 512 -> 28 (16 lanes per output)
        int o = t >> 4, c = t & 15;
        if (o < 28) {
            float acc = 0.f;
            for (int k = c; k < 512; k += 16) acc = fmaf(W6[o * 512 + k], h5[k], acc);
            acc += __shfl_xor(acc, 1);
            acc += __shfl_xor(acc, 2);
            acc += __shfl_xor(acc, 4);
            acc += __shfl_xor(acc, 8);
            if (c == 0) logits[o] = acc + b6[o];
        }
    }
    __syncthreads();
    if (t == 0) {
        float mx = -1e30f;
        for (int cc = 0; cc < 28; ++cc) mx = fmaxf(mx, logits[cc]);
        float se = 0.f;
        for (int cc = 0; cc < 28; ++cc) se += expf(logits[cc] - mx);
        red[0] = mx; red[1] = logf(se);
    }
    __syncthreads();
    if (t < 28) out[b * 28 + t] = logits[t] - red[0] - red[1];
}

extern "C" void kernel_launch(void* const* d_in, const int* in_sizes, int n_in,
                              void* d_out, int out_size, void* d_ws, size_t ws_size,
                              hipStream_t stream)
{
    const float* x   = (const float*)d_in[0];
    const float* qst = (const float*)d_in[1];
    const float* W0  = (const float*)d_in[2];
    const float* b0  = (const float*)d_in[3];
    const float* W1  = (const float*)d_in[4];
    const float* b1  = (const float*)d_in[5];
    const float* W2  = (const float*)d_in[6];
    const float* b2  = (const float*)d_in[7];
    const float* W3  = (const float*)d_in[8];
    const float* b3  = (const float*)d_in[9];
    const float* W4  = (const float*)d_in[10];
    const float* b4  = (const float*)d_in[11];
    const float* W5  = (const float*)d_in[12];
    const float* b5  = (const float*)d_in[13];
    const float* W6  = (const float*)d_in[14];
    const float* b6  = (const float*)d_in[15];
    float* out = (float*)d_out;

    char* ws = (char*)d_ws;
    float*          Uu  = (float*)(ws);                     // 4 MiB
    float*          Vv  = (float*)(ws + 4194304);           // 4 MiB
    unsigned short* Wp  = (unsigned short*)(ws + 8388608);  // 1.5 MiB
    float*          W4t = (float*)(ws + 9961472);           // 1.5 MiB
    float*          W5t = (float*)(ws + 11534336);          // 1 MiB
    float*          S   = (float*)(ws + 12582912);          // 64 KiB

    k_prep <<<NPREP_BLOCKS, 256, 0, stream>>>(W1, W2, W3, W0, W4, W5, x, b0,
                                              Wp, W4t, W5t, S, Uu, Vv);
    k_fused<<<2048, 512, 0, stream>>>(Uu, Vv, Wp, b1, b2, b3, S);
    k_tail <<<32, 512, 0, stream>>>(S, qst, W4t, b4, W5t, b5, W6, b6, out);
}

// Round 10
// 518.622 us; speedup vs baseline: 1.2765x; 1.2765x over previous
//
#include <hip/hip_runtime.h>
#include <hip/hip_bf16.h>
#include <math.h>

// Relational Network fused pipeline for MI355X (gfx950).
// B=32, D=64, K=26, QST=256, G=[512x6, 28], AGG at layer 4.
//
// Round 10: consolidation of all measured-good pieces.
//  - Wp PHYSICAL layout back to round-5 form ([l][n16][s][lane][j]): the
//    round-7 relayout ([wv][s][jj][lane][j]) is what blew FETCH 85->470MB
//    (L2 hit collapse on the 3GB logical W stream); correlates across
//    r7(no swizzle,470) / r8(swizzle,424) / r9(async,292) vs r5(85).
//  - Transposed MFMA compute + ds_write_b64 epilogue kept (killed the
//    ~110MB/dispatch scratch spill: WRITE 0.8MB in r8).
//  - Synchronous load-then-use K-loop, #pragma unroll 1 (proven L2-friendly).
//  - NO XCD swizzle, NO async global_load_lds, 64KB LDS, launch_bounds(512,4)
//    -> 2 blocks/CU, 16 waves/CU.

typedef __attribute__((ext_vector_type(8))) short bf16x8;   // 8 bf16 in 4 VGPRs
typedef __attribute__((ext_vector_type(4))) float f32x4;    // MFMA 16x16 accumulator

__device__ __forceinline__ unsigned short f2bf(float f) {
    union { float f; unsigned u; } x; x.f = f;
    unsigned r = x.u + 0x7fffu + ((x.u >> 16) & 1u);   // RNE
    return (unsigned short)(r >> 16);
}

#define MFMA16(a, b, c) __builtin_amdgcn_mfma_f32_16x16x32_bf16(a, b, c, 0, 0, 0)

// ---------------- prep ----------------
// Wp layout per layer (round-5 form): flat = ((n16*16 + s)*64 + lane)*8 + j,
//   value = W[n][k], n = n16*16 + (lane&15), k = s*32 + (lane>>4)*8 + j.
// Block ranges: [0,384) Wp pack | [384,768) W4 transpose | [768,1024) W5
//               transpose | [1024,1088) S=0 | [1088,1600) U/V
__global__ void k_prep(const float* __restrict__ W1, const float* __restrict__ W2,
                       const float* __restrict__ W3, const float* __restrict__ W0,
                       const float* __restrict__ W4, const float* __restrict__ W5,
                       const float* __restrict__ x,  const float* __restrict__ b0,
                       unsigned short* __restrict__ Wp,   // [3][262144] bf16
                       float* __restrict__ W4t,           // [768][512] fp32
                       float* __restrict__ W5t,           // [512][512] fp32
                       float* __restrict__ S,             // [32][512] fp32 (zeroed)
                       float* __restrict__ U, float* __restrict__ V)
{
    int bi = blockIdx.x;
    int t = threadIdx.x;
    if (bi < 384) {
        // one thread = one 8-elem fragment run (16B write-coalesced)
        int T = bi * 256 + t;                 // [0, 98304)
        int l = T >> 15, r = T & 32767;
        int lane = r & 63, s = (r >> 6) & 15, n16 = r >> 10;
        int n  = n16 * 16 + (lane & 15);
        int kb = s * 32 + (lane >> 4) * 8;
        const float* W = (l == 0) ? W1 : (l == 1) ? W2 : W3;
        const float4* src = (const float4*)&W[n * 512 + kb];
        float4 v0 = src[0], v1 = src[1];
        ushort4 p0, p1;
        p0.x = f2bf(v0.x); p0.y = f2bf(v0.y); p0.z = f2bf(v0.z); p0.w = f2bf(v0.w);
        p1.x = f2bf(v1.x); p1.y = f2bf(v1.y); p1.z = f2bf(v1.z); p1.w = f2bf(v1.w);
        ushort4* dst = (ushort4*)&Wp[(size_t)T * 8];
        dst[0] = p0; dst[1] = p1;
    } else if (bi < 768) {
        // W4 [512][768] -> W4t [768][512], 32x32 LDS tiles, both sides coalesced
        int tile = bi - 384;                  // 0..383 = 24 (k) x 16 (o)
        int tk = tile % 24, to = tile / 24;
        __shared__ float tl[32][33];
        int tx = t & 31, ty = t >> 5;         // 32 x 8
        #pragma unroll
        for (int i = 0; i < 4; ++i)
            tl[ty + i * 8][tx] = W4[(to * 32 + ty + i * 8) * 768 + tk * 32 + tx];
        __syncthreads();
        #pragma unroll
        for (int i = 0; i < 4; ++i)
            W4t[(tk * 32 + ty + i * 8) * 512 + to * 32 + tx] = tl[tx][ty + i * 8];
    } else if (bi < 1024) {
        // W5 [512][512] -> W5t transpose
        int tile = bi - 768;                  // 0..255 = 16 x 16
        int tk = tile & 15, to = tile >> 4;
        __shared__ float tl[32][33];
        int tx = t & 31, ty = t >> 5;
        #pragma unroll
        for (int i = 0; i < 4; ++i)
            tl[ty + i * 8][tx] = W5[(to * 32 + ty + i * 8) * 512 + tk * 32 + tx];
        __syncthreads();
        #pragma unroll
        for (int i = 0; i < 4; ++i)
            W5t[(tk * 32 + ty + i * 8) * 512 + to * 32 + tx] = tl[tx][ty + i * 8];
    } else if (bi < 1088) {
        S[(bi - 1024) * 256 + t] = 0.f;
    } else {
        // ---- U/V: 512 blocks, one per (b, qg, half) ----
        int id = bi - 1088;
        int b = id >> 4, qg = (id >> 1) & 7, half = id & 1;
        __shared__ float xs[8][26];
        if (t < 8 * 26) xs[t / 26][t % 26] = x[(b * 64 + qg * 8 + t / 26) * 26 + t % 26];
        __syncthreads();
        int o = half * 256 + t;
        float u[8] = {0,0,0,0,0,0,0,0}, v[8] = {0,0,0,0,0,0,0,0};
        for (int k = 0; k < 26; ++k) {
            float wa = W0[o * 52 + k];
            float wb = W0[o * 52 + 26 + k];
            #pragma unroll
            for (int q = 0; q < 8; ++q) {
                u[q] = fmaf(xs[q][k], wa, u[q]);
                v[q] = fmaf(xs[q][k], wb, v[q]);
            }
        }
        float bb = b0[o];
        #pragma unroll
        for (int q = 0; q < 8; ++q) {
            U[(size_t)((b * 64 + qg * 8 + q)) * 512 + o] = u[q] + bb;  // b0 folded into U
            V[(size_t)((b * 64 + qg * 8 + q)) * 512 + o] = v[q];
        }
    }
}
#define NPREP_BLOCKS 1600

// ---------------- fused heavy layers 1..3 (transposed compute) ----------------
// One block per (b,p): 64 pair-rows m. h tile 64x512 bf16 in LDS, XOR-swizzled
// 16B granules: (m,k) at m*512 + ((k>>3)^(m&7))*8 + (k&7).
// 8 waves; wave w computes out-features n in [w*64, w*64+64):
// acc[nt][mt_]: n = w*64 + nt*16 + q4*4 + r, m = mt_*16 + i16.
__global__ __launch_bounds__(512, 4) void k_fused(
    const float* __restrict__ U, const float* __restrict__ V,
    const unsigned short* __restrict__ Wp,
    const float* __restrict__ b1, const float* __restrict__ b2, const float* __restrict__ b3,
    float* __restrict__ S)
{
    __shared__ unsigned short hsm[64 * 512];   // 64 KiB
    int t = threadIdx.x;
    int blk = blockIdx.x;
    int b = blk >> 6, p = blk & 63;            // NO swizzle (plain dispatch order)

    // ---- stage h0 = relu(U[b,q,:] + V[b,p,:]) into LDS (bf16, swizzled) ----
    const float4* U4 = (const float4*)(U + (size_t)(b * 64) * 512);
    const float4* V4 = (const float4*)(V + (size_t)(b * 64 + p) * 512);
    #pragma unroll 1
    for (int it = 0; it < 16; ++it) {
        int f = it * 512 + t;
        int q = f >> 7, oq = f & 127;
        float4 uu = U4[q * 128 + oq];
        float4 vv = V4[oq];
        ushort4 pk;
        pk.x = f2bf(fmaxf(uu.x + vv.x, 0.f));
        pk.y = f2bf(fmaxf(uu.y + vv.y, 0.f));
        pk.z = f2bf(fmaxf(uu.z + vv.z, 0.f));
        pk.w = f2bf(fmaxf(uu.w + vv.w, 0.f));
        int g = oq >> 1, hh = oq & 1;
        *(ushort4*)&hsm[q * 512 + ((g ^ (q & 7)) << 3) + hh * 4] = pk;
    }

    int wave = t >> 6, lane = t & 63;
    int i16 = lane & 15, q4 = lane >> 4;
    int xr = i16 & 7;                       // m-invariant part of the swizzle

    #pragma unroll 1
    for (int l = 0; l < 3; ++l) {
        const float* bl = (l == 0) ? b1 : (l == 1) ? b2 : b3;
        __syncthreads();   // h ready

        f32x4 acc[4][4];   // [nt][mt_]
        #pragma unroll
        for (int nt = 0; nt < 4; ++nt)
            #pragma unroll
            for (int mt_ = 0; mt_ < 4; ++mt_)
                acc[nt][mt_] = (f32x4){0.f, 0.f, 0.f, 0.f};

        // W fragments (A-operand), round-5 physical layout:
        // w[nt] at Wb + nt*8192 + s*512 shorts (nt stride 16KB, s stride 1KB).
        const unsigned short* Wb = Wp + (size_t)l * 262144 + wave * 32768 + lane * 8;
        // h fragments (B-operand): one shared LDS base; mt_ at +8192 shorts.
        const unsigned short* Ab0 = &hsm[i16 * 512];

        #pragma unroll 1
        for (int s = 0; s < 16; ++s) {
            bf16x8 w[4], a[4];
            const unsigned short* Ws = Wb + s * 512;
            #pragma unroll
            for (int nt = 0; nt < 4; ++nt)
                w[nt] = *(const bf16x8*)(Ws + nt * 8192);
            int g = ((s * 4 + q4) ^ xr) * 8;
            #pragma unroll
            for (int mt_ = 0; mt_ < 4; ++mt_)
                a[mt_] = *(const bf16x8*)(Ab0 + g + mt_ * 8192);
            #pragma unroll
            for (int nt = 0; nt < 4; ++nt)
                #pragma unroll
                for (int mt_ = 0; mt_ < 4; ++mt_)
                    acc[nt][mt_] = MFMA16(w[nt], a[mt_], acc[nt][mt_]);
        }
        __syncthreads();   // all reads of h done before overwrite

        if (l < 2) {
            // bias + relu -> 4 consecutive n per thread -> ds_write_b64
            #pragma unroll 1
            for (int nt = 0; nt < 4; ++nt) {
                float4 bb = *(const float4*)&bl[wave * 64 + nt * 16 + q4 * 4];
                int G = wave * 8 + nt * 2 + (q4 >> 1);    // n-granule index
                int nin = (q4 & 1) * 4;                   // short offset in granule
                #pragma unroll
                for (int mt_ = 0; mt_ < 4; ++mt_) {
                    int m = mt_ * 16 + i16;
                    ushort4 pk;
                    pk.x = f2bf(fmaxf(acc[nt][mt_][0] + bb.x, 0.f));
                    pk.y = f2bf(fmaxf(acc[nt][mt_][1] + bb.y, 0.f));
                    pk.z = f2bf(fmaxf(acc[nt][mt_][2] + bb.z, 0.f));
                    pk.w = f2bf(fmaxf(acc[nt][mt_][3] + bb.w, 0.f));
                    *(ushort4*)&hsm[m * 512 + ((G ^ (m & 7)) << 3) + nin] = pk;
                }
            }
        } else {
            // layer 3: bias + relu + sum over all 64 m -> atomicAdd S[b][n]
            #pragma unroll 1
            for (int nt = 0; nt < 4; ++nt) {
                float4 bb = *(const float4*)&bl[wave * 64 + nt * 16 + q4 * 4];
                float s0 = 0.f, s1 = 0.f, s2s = 0.f, s3 = 0.f;
                #pragma unroll
                for (int mt_ = 0; mt_ < 4; ++mt_) {
                    s0 += fmaxf(acc[nt][mt_][0] + bb.x, 0.f);
                    s1 += fmaxf(acc[nt][mt_][1] + bb.y, 0.f);
                    s2s += fmaxf(acc[nt][mt_][2] + bb.z, 0.f);
                    s3 += fmaxf(acc[nt][mt_][3] + bb.w, 0.f);
                }
                #pragma unroll
                for (int d = 1; d < 16; d <<= 1) {
                    s0 += __shfl_xor(s0, d);
                    s1 += __shfl_xor(s1, d);
                    s2s += __shfl_xor(s2s, d);
                    s3 += __shfl_xor(s3, d);
                }
                if (i16 == 0) {
                    float* dst = &S[b * 512 + wave * 64 + nt * 16 + q4 * 4];
                    atomicAdd(dst + 0, s0);
                    atomicAdd(dst + 1, s1);
                    atomicAdd(dst + 2, s2s);
                    atomicAdd(dst + 3, s3);
                }
            }
        }
    }
}

// ---------------- tail: layers 4,5,6 + log_softmax (one block per batch) ----
__global__ __launch_bounds__(512) void k_tail(
    const float* __restrict__ S, const float* __restrict__ qst,
    const float* __restrict__ W4t, const float* __restrict__ b4,
    const float* __restrict__ W5t, const float* __restrict__ b5,
    const float* __restrict__ W6, const float* __restrict__ b6,
    float* __restrict__ out)
{
    int b = blockIdx.x, t = threadIdx.x;
    __shared__ float z[768];
    __shared__ float h4[512];
    __shared__ float h5[512];
    __shared__ float logits[28];
    __shared__ float red[2];

    for (int i = t; i < 768; i += 512)
        z[i] = (i < 512) ? S[b * 512 + i] : qst[b * 256 + (i - 512)];
    __syncthreads();
    {   // layer 4: 768 -> 512, relu
        float acc = b4[t];
        for (int k = 0; k < 768; ++k) acc = fmaf(W4t[k * 512 + t], z[k], acc);
        h4[t] = fmaxf(acc, 0.f);
    }
    __syncthreads();
    {   // layer 5: 512 -> 512, relu
        float acc = b5[t];
        for (int k = 0; k < 512; ++k) acc = fmaf(W5t[k * 512 + t], h4[k], acc);
        h5[t] = fmaxf(acc, 0.f);
    }
    __syncthreads();
    {   // layer 6: 512 -> 28 (16 lanes per output)
        int o = t >> 4, c = t & 15;
        if (o < 28) {
            float acc = 0.f;
            for (int k = c; k < 512; k += 16) acc = fmaf(W6[o * 512 + k], h5[k], acc);
            acc += __shfl_xor(acc, 1);
            acc += __shfl_xor(acc, 2);
            acc += __shfl_xor(acc, 4);
            acc += __shfl_xor(acc, 8);
            if (c == 0) logits[o] = acc + b6[o];
        }
    }
    __syncthreads();
    if (t == 0) {
        float mx = -1e30f;
        for (int cc = 0; cc < 28; ++cc) mx = fmaxf(mx, logits[cc]);
        float se = 0.f;
        for (int cc = 0; cc < 28; ++cc) se += expf(logits[cc] - mx);
        red[0] = mx; red[1] = logf(se);
    }
    __syncthreads();
    if (t < 28) out[b * 28 + t] = logits[t] - red[0] - red[1];
}

extern "C" void kernel_launch(void* const* d_in, const int* in_sizes, int n_in,
                              void* d_out, int out_size, void* d_ws, size_t ws_size,
                              hipStream_t stream)
{
    const float* x   = (const float*)d_in[0];
    const float* qst = (const float*)d_in[1];
    const float* W0  = (const float*)d_in[2];
    const float* b0  = (const float*)d_in[3];
    const float* W1  = (const float*)d_in[4];
    const float* b1  = (const float*)d_in[5];
    const float* W2  = (const float*)d_in[6];
    const float* b2  = (const float*)d_in[7];
    const float* W3  = (const float*)d_in[8];
    const float* b3  = (const float*)d_in[9];
    const float* W4  = (const float*)d_in[10];
    const float* b4  = (const float*)d_in[11];
    const float* W5  = (const float*)d_in[12];
    const float* b5  = (const float*)d_in[13];
    const float* W6  = (const float*)d_in[14];
    const float* b6  = (const float*)d_in[15];
    float* out = (float*)d_out;

    char* ws = (char*)d_ws;
    float*          Uu  = (float*)(ws);                     // 4 MiB
    float*          Vv  = (float*)(ws + 4194304);           // 4 MiB
    unsigned short* Wp  = (unsigned short*)(ws + 8388608);  // 1.5 MiB
    float*          W4t = (float*)(ws + 9961472);           // 1.5 MiB
    float*          W5t = (float*)(ws + 11534336);          // 1 MiB
    float*          S   = (float*)(ws + 12582912);          // 64 KiB

    k_prep <<<NPREP_BLOCKS, 256, 0, stream>>>(W1, W2, W3, W0, W4, W5, x, b0,
                                              Wp, W4t, W5t, S, Uu, Vv);
    k_fused<<<2048, 512, 0, stream>>>(Uu, Vv, Wp, b1, b2, b3, S);
    k_tail <<<32, 512, 0, stream>>>(S, qst, W4t, b4, W5t, b5, W6, b6, out);
}